// Round 2
// baseline (2668.492 us; speedup 1.0000x reference)
//
#include <hip/hip_runtime.h>
#include <math.h>

// KanLayer: out[o] = sum_i sum_k c[i,o,k] * B[i,k]
// x: (2048,) fp32 in [0,1); c: (2048, 4096, 61) fp32; out: (4096,) fp32.
// B is a degree-2 B-spline basis: each row B[i,:] has <=3 nonzeros at
// k = j-2..j (t_j <= x_i < t_{j+1}), right-edge truncated.
//
// v2 lesson: the 16B-per-244B gather is DRAM-inefficiency-bound (~0.6 TB/s
// effective vs 6.2 TB/s sequential on this chip) -- NOT concurrency-bound.
// v3: dense sequential streaming. Each block owns 256 o's x 32 i's; per i it
// cooperatively streams the contiguous 62.5 KB chunk c[i, o0:o0+256, :] into
// LDS with coalesced float4 loads, then each thread gathers its 4-float
// window from LDS (stride 61 floats -> 61 % 32 = 29, gcd(29,32)=1 -> exactly
// 2-way bank aliasing, which is free on CDNA4). 3x the bytes of the sparse
// gather, ~10x the effective bandwidth.

#define INPUT_DIM 2048
#define OUT_DIM   4096
#define N_COEF    61
#define OB        256                 // o's per block (grid.x = 16)
#define IG        32                  // i's per block  (grid.y = 64)
#define CHUNK_F   (OB * N_COEF)       // 15616 floats = 62464 B per i-chunk
#define CHUNK_V4  (CHUNK_F / 4)       // 3904 float4 (exactly; 16B-aligned base)

__device__ __forceinline__ float Tk(int k) {
    // matches jnp.linspace(-1, 1, 64) to within 1 ulp
    return -1.0f + (float)k * (2.0f / 63.0f);
}

__global__ void kan_zero_kernel(float* __restrict__ out) {
    out[blockIdx.x * blockDim.x + threadIdx.x] = 0.0f;
}

__global__ __launch_bounds__(OB) void kan_kernel(const float* __restrict__ x,
                                                 const float* __restrict__ c,
                                                 float* __restrict__ out) {
    __shared__ float4 ldsv[CHUNK_V4];          // 62464 B staging buffer
    __shared__ int    sk0[IG];
    __shared__ float4 sw[IG];

    const int tid    = threadIdx.x;
    const int o0     = blockIdx.x * OB;
    const int i_base = blockIdx.y * IG;

    if (tid < IG) {
        const float xv = x[i_base + tid];
        // interval index j: t_j <= xv < t_{j+1}
        int j = (int)floorf((xv + 1.0f) * 31.5f);
        j = max(0, min(62, j));
        while (j > 0  && xv <  Tk(j))     --j;   // <=1 iter fixups
        while (j < 62 && xv >= Tk(j + 1)) ++j;

        const float tjm1 = Tk(j - 1), tj = Tk(j), tj1 = Tk(j + 1), tj2 = Tk(j + 2);
        // Cox-de Boor, degree 1 then degree 2 (identical to verified v2):
        const float b1l = (tj1 - xv) / (tj1 - tj);   // B1_{j-1}
        const float b1r = (xv - tj)  / (tj1 - tj);   // B1_j
        const float w0 = (tj1 - xv) / (tj1 - tjm1) * b1l;                       // B2_{j-2}
        const float w1 = (xv - tjm1) / (tj1 - tjm1) * b1l
                       + (tj2 - xv) / (tj2 - tj)    * b1r;                      // B2_{j-1}
        const float w2 = (xv - tj)  / (tj2 - tj)    * b1r;                      // B2_j

        // 4-wide window [k0, k0+3], k0 in [0,57] so k0+3 <= 60 stays in-row;
        // truncated basis entries get weight 0.
        int s = j - 59; if (s < 0) s = 0;
        int k0 = j - 2 - s; if (k0 < 0) k0 = 0;
        const float wsrc[3] = {w0, w1, w2};
        float ww[4] = {0.0f, 0.0f, 0.0f, 0.0f};
        #pragma unroll
        for (int m = 0; m < 3; ++m) {
            const int l = (j - 2 + m) - k0;
            if (0 <= l && l < 4) ww[l] = wsrc[m];
        }
        sk0[tid] = k0;
        sw[tid]  = make_float4(ww[0], ww[1], ww[2], ww[3]);
    }
    __syncthreads();

    const float* ldsf = (const float*)ldsv;
    float acc = 0.0f;

    for (int ii = 0; ii < IG; ++ii) {
        // ---- Phase 1: dense coalesced stream of c[i, o0:o0+256, :] -> LDS.
        // Base offset ((i*4096 + o0) * 61) is a multiple of 4 floats -> the
        // float4 view is 16B-aligned; chunk is exactly 3904 float4s.
        const float4* src = (const float4*)(c + ((long long)(i_base + ii) * OUT_DIM + o0)
                                                  * (long long)N_COEF);
        for (int idx = tid; idx < CHUNK_V4; idx += OB) {
            ldsv[idx] = src[idx];
        }
        __syncthreads();

        // ---- Phase 2: per-thread 4-float window gather from LDS.
        const int    k0 = sk0[ii];
        const float4 w  = sw[ii];
        const float* row = ldsf + tid * N_COEF + k0;
        acc = fmaf(row[0], w.x, acc);
        acc = fmaf(row[1], w.y, acc);
        acc = fmaf(row[2], w.z, acc);
        acc = fmaf(row[3], w.w, acc);
        __syncthreads();   // protect LDS before next iteration's overwrite
    }

    atomicAdd(&out[o0 + tid], acc);
}

extern "C" void kernel_launch(void* const* d_in, const int* in_sizes, int n_in,
                              void* d_out, int out_size, void* d_ws, size_t ws_size,
                              hipStream_t stream) {
    const float* x   = (const float*)d_in[0];
    const float* c   = (const float*)d_in[1];
    float*       out = (float*)d_out;

    hipLaunchKernelGGL(kan_zero_kernel, dim3(OUT_DIM / 256), dim3(256), 0, stream, out);

    dim3 grid(OUT_DIM / OB, INPUT_DIM / IG);   // 16 x 64 = 1024 blocks
    hipLaunchKernelGGL(kan_kernel, grid, dim3(OB), 0, stream, x, c, out);
}